// Round 3
// baseline (1073.926 us; speedup 1.0000x reference)
//
#include <hip/hip_runtime.h>
#include <math.h>

#define BGR 256        // graphs
#define NPG0 400       // nodes per graph
#define NN (BGR*NPG0)  // 102400 nodes
#define NE (NN*16)     // 1638400 edges
#define HD 128
#define CAP 64         // CSR capacity (pools only)
#define AST 432        // dense adjacency row stride (bytes); 416 used (13*32), padded for LDS banks
#define KSA 13         // agg k-steps (13*32 = 416)
#define MSTR 136       // mean LDS row stride (shorts), 16B-aligned
#define NTPB 5         // node-tiles (of 16) per block; 5 blocks cover a graph
#define ABYTES (NTPB*16*AST)        // 34560 bytes staged adjacency per block
#define ACHUNK (ABYTES/16)          // 2160 16B chunks
#define SCGRID 2048    // k_scale grid

typedef __attribute__((ext_vector_type(8))) short short8;
typedef __attribute__((ext_vector_type(4))) float floatx4;

__device__ __forceinline__ unsigned short f2b(float f) {
    unsigned int u = __builtin_bit_cast(unsigned int, f);
    unsigned int r = (u + 0x7fffu + ((u >> 16) & 1u)) >> 16;
    return (unsigned short)r;
}
__device__ __forceinline__ unsigned int pk2(float a, float b) {
    return (unsigned int)f2b(a) | ((unsigned int)f2b(b) << 16);
}
__device__ __forceinline__ float b2f_lo(unsigned int u) { return __builtin_bit_cast(float, u << 16); }
__device__ __forceinline__ float b2f_hi(unsigned int u) { return __builtin_bit_cast(float, u & 0xffff0000u); }
__device__ __forceinline__ short bfint(unsigned int v) {
    // exact bf16 of small nonneg int (v < 256)
    return (short)(__builtin_bit_cast(unsigned int, (float)v) >> 16);
}
__device__ __forceinline__ short8 ub8_bf16(uint2 u) {
    short8 r;
    r[0] = bfint(u.x & 0xffu);        r[1] = bfint((u.x >> 8) & 0xffu);
    r[2] = bfint((u.x >> 16) & 0xffu); r[3] = bfint(u.x >> 24);
    r[4] = bfint(u.y & 0xffu);        r[5] = bfint((u.y >> 8) & 0xffu);
    r[6] = bfint((u.y >> 16) & 0xffu); r[7] = bfint(u.y >> 24);
    return r;
}

// ---------------- CSR build (pools only) ----------------
__global__ void k_build(const int* __restrict__ src, const int* __restrict__ dst,
                        int* __restrict__ cnt, int* __restrict__ col) {
    int e = blockIdx.x * 256 + threadIdx.x;
    if (e >= NE) return;
    int d = dst[e], s = src[e];
    int i = atomicAdd(&cnt[d], 1);
    if (i < CAP) col[d * CAP + i] = s;
}

// ---------------- dense adjacency build: A_u8[dst][src_local] += 1 (packed atomics)
__global__ void k_abuild(const int* __restrict__ src, const int* __restrict__ dst,
                         unsigned int* __restrict__ A) {
    int e = blockIdx.x * 256 + threadIdx.x;
    if (e >= NE) return;
    int s = src[e], d = dst[e];
    int g = d / NPG0;
    long idx = (long)d * AST + (s - g * NPG0);   // byte index
    atomicAdd(&A[idx >> 2], 1u << ((idx & 3) * 8));
}

// alive=1, rliv = 1/max(deg,1) (exact degree incl. multi-edges)
__global__ void k_initrl(const int* __restrict__ cnt, float* __restrict__ alive,
                         float* __restrict__ rliv) {
    int i = blockIdx.x * 256 + threadIdx.x;
    if (i >= NN) return;
    alive[i] = 1.0f;
    rliv[i] = 1.0f / fmaxf((float)cnt[i], 1.0f);
}

// ---------------- W -> bf16, transposed: bt[m][j*128 + f] = bf16(W_m[f*128 + j]) = W^T row-major
__global__ void k_wcvt(const float* __restrict__ c1_wr, const float* __restrict__ c1_ws,
                       const float* __restrict__ cs_wr, const float* __restrict__ cs_ws,
                       unsigned short* __restrict__ bt) {
    int m = blockIdx.y;
    int idx = blockIdx.x * 256 + threadIdx.x;
    const float* W = (m == 0) ? c1_wr : (m == 1) ? c1_ws
                   : (m < 6) ? (cs_wr + (m - 2) * HD * HD) : (cs_ws + (m - 6) * HD * HD);
    int n = idx >> 7, k = idx & 127;
    bt[m * HD * HD + idx] = f2b(W[k * HD + n]);
}

// ---------------- one-time input transpose: x_in fp32 [NN][128] -> xT bf16 [128][NN]
__global__ __launch_bounds__(512) void k_xt0(const float* __restrict__ xin,
                                             unsigned short* __restrict__ xt) {
    int t = threadIdx.x;
    int ngrp = blockIdx.x * 128 + (t >> 2);   // node group (4 nodes)
    int j = t & 3;
    int r0 = ngrp * 4;
    int f0 = blockIdx.y * 4;                  // feature group (4 feats)
    float4 v = ((const float4*)xin)[(long)(r0 + j) * 32 + (f0 >> 2)];
    float a0 = v.x, a1 = v.y, a2 = v.z, a3 = v.w;
    float tw;
    bool bo1 = j & 1;
    tw = __shfl_xor(bo1 ? a0 : a1, 1); if (bo1) a0 = tw; else a1 = tw;
    tw = __shfl_xor(bo1 ? a2 : a3, 1); if (bo1) a2 = tw; else a3 = tw;
    bool bo2 = (j & 2) != 0;
    tw = __shfl_xor(bo2 ? a0 : a2, 2); if (bo2) a0 = tw; else a2 = tw;
    tw = __shfl_xor(bo2 ? a1 : a3, 2); if (bo2) a1 = tw; else a3 = tw;
    uint2 w; w.x = pk2(a0, a1); w.y = pk2(a2, a3);
    *(uint2*)&xt[(long)(f0 + j) * NN + r0] = w;
}

// ---------------- fused layer v5: grid (BGR x 5 node-groups), 256 threads (4 waves).
//  - adjacency tile (80 rows x 432B = 34.5KB) bulk-staged to LDS at block start
//    (9 independent dwordx4 loads/thread -> HBM latency paid once, not 13x chained)
//  - phase A k-loop reads adjacency from LDS (row stride 432B: 108 dwords %32=12 -> <=2-way, free)
//  - sM (mean tile) aliases the staging buffer after a barrier (acc lives in AGPRs)
//  - optional pool-score dot epilogue: dd[n][mp][2] = per-wave partial of x@p_wr / x@p_ws
template<bool XF32>
__global__ __launch_bounds__(256, 4) void k_layer5(
    const void* __restrict__ xin_v, unsigned short* __restrict__ xout,
    const unsigned short* __restrict__ xtin, unsigned short* __restrict__ xtout,
    const unsigned char* __restrict__ Amat,
    const float* __restrict__ alive, const float* __restrict__ rliv,
    const unsigned short* __restrict__ wr_bt, const unsigned short* __restrict__ ws_bt,
    const float* __restrict__ bias, float* __restrict__ hcat, int layer,
    const float* __restrict__ pwr, const float* __restrict__ pws, float* __restrict__ dd)
{
    __shared__ __align__(16) unsigned char sU8[ABYTES];   // 34560 B; phase A: adjacency, phase B: sM
    unsigned short* sM = (unsigned short*)sU8;            // 80 x 136 shorts = 21760 B (aliased)
    int g = blockIdx.x;
    int ntg = blockIdx.y;
    int t = threadIdx.x;
    long gbase = (long)g * NPG0;
    int lane = t & 63, wid = t >> 6;          // 4 waves
    int quad = lane >> 4, l15 = lane & 15;
    int mp = wid;                              // feature pair-group: m-tiles 2mp, 2mp+1
    int nbase = ntg * (NTPB * 16);             // local dst-node base (0,80,160,240,320)

    // ---- stage adjacency tile: 2160 x 16B chunks, all loads independent & in flight
    const unsigned char* Ag = Amat + (gbase + nbase) * (long)AST;
    {
        const uint4* Ag4 = (const uint4*)Ag;
        uint4 stg[9];
#pragma unroll
        for (int r = 0; r < 9; ++r) {
            int c = t + r * 256;
            if (c < ACHUNK) stg[r] = Ag4[c];
        }
#pragma unroll
        for (int r = 0; r < 9; ++r) {
            int c = t + r * 256;
            if (c < ACHUNK) *(uint4*)&sU8[c * 16] = stg[r];
        }
    }

    float rl[NTPB];
#pragma unroll
    for (int nt = 0; nt < NTPB; ++nt) rl[nt] = rliv[gbase + nbase + nt * 16 + l15];

    const unsigned short* xa0 = xtin + (long)(mp * 32 + l15) * NN + gbase;
    const unsigned short* xa1 = xa0 + (long)16 * NN;
    short8 A0c = *(const short8*)&xa0[quad * 8];
    short8 A1c = *(const short8*)&xa1[quad * 8];

    __syncthreads();   // staged adjacency visible

    // ---- phase A: agg GEMM; adjacency from LDS, xT depth-1 prefetched
    floatx4 acc[NTPB][2];
#pragma unroll
    for (int nt = 0; nt < NTPB; ++nt) {
        acc[nt][0] = (floatx4){0.f, 0.f, 0.f, 0.f};
        acc[nt][1] = (floatx4){0.f, 0.f, 0.f, 0.f};
    }
    int abase = l15 * AST + quad * 8;          // per-lane LDS byte base

#pragma unroll
    for (int k = 0; k < KSA; ++k) {
        short8 A0n, A1n;
        if (k + 1 < KSA) {
            int ko = (k + 1) * 32 + quad * 8;
            A0n = *(const short8*)&xa0[ko];
            A1n = *(const short8*)&xa1[ko];
        }
#pragma unroll
        for (int nt = 0; nt < NTPB; ++nt) {
            uint2 u = *(const uint2*)&sU8[abase + nt * (16 * AST) + k * 32];
            short8 Bf = ub8_bf16(u);
            acc[nt][0] = __builtin_amdgcn_mfma_f32_16x16x32_bf16(A0c, Bf, acc[nt][0], 0, 0, 0);
            acc[nt][1] = __builtin_amdgcn_mfma_f32_16x16x32_bf16(A1c, Bf, acc[nt][1], 0, 0, 0);
        }
        if (k + 1 < KSA) { A0c = A0n; A1c = A1n; }
    }
    __syncthreads();   // all adjacency LDS reads complete; sU8 may be overwritten as sM

    // scale by rliv, write mean tile to LDS (node-major, local rows)
#pragma unroll
    for (int nt = 0; nt < NTPB; ++nt) {
        int lo = nt * 16 + l15;
        unsigned short* mrow = &sM[lo * MSTR + 32 * mp + quad * 4];
        uint2 w0, w1;
        w0.x = pk2(acc[nt][0][0] * rl[nt], acc[nt][0][1] * rl[nt]);
        w0.y = pk2(acc[nt][0][2] * rl[nt], acc[nt][0][3] * rl[nt]);
        w1.x = pk2(acc[nt][1][0] * rl[nt], acc[nt][1][1] * rl[nt]);
        w1.y = pk2(acc[nt][1][2] * rl[nt], acc[nt][1][3] * rl[nt]);
        *(uint2*)mrow = w0;
        *(uint2*)(mrow + 16) = w1;
    }

    // ---- pre-barrier issue: W frags, bias, alive, pool weights, nt=0 x rows
    short8 Wr8[2][4], Ws8[2][4];
#pragma unroll
    for (int mt = 0; mt < 2; ++mt) {
        int jj = (2 * mp + mt) * 16 + l15;
#pragma unroll
        for (int k = 0; k < 4; ++k) {
            Wr8[mt][k] = *(const short8*)&wr_bt[jj * HD + k * 32 + quad * 8];
            Ws8[mt][k] = *(const short8*)&ws_bt[jj * HD + k * 32 + quad * 8];
        }
    }
    float4 b40 = *(const float4*)&bias[(2 * mp) * 16 + quad * 4];
    float4 b41 = *(const float4*)&bias[(2 * mp + 1) * 16 + quad * 4];
    float av[NTPB];
#pragma unroll
    for (int nt = 0; nt < NTPB; ++nt) av[nt] = alive[gbase + nbase + nt * 16 + l15];

    float4 pwrA, pwrB, pwsA, pwsB;
    if (dd) {
        pwrA = *(const float4*)&pwr[(2 * mp) * 16 + quad * 4];
        pwrB = *(const float4*)&pwr[(2 * mp + 1) * 16 + quad * 4];
        pwsA = *(const float4*)&pws[(2 * mp) * 16 + quad * 4];
        pwsB = *(const float4*)&pws[(2 * mp + 1) * 16 + quad * 4];
    }

    short8 xc[4];
    if (!XF32) {
        const unsigned short* x16 = (const unsigned short*)xin_v;
        long go0 = gbase + nbase + l15;
#pragma unroll
        for (int k = 0; k < 4; ++k)
            xc[k] = *(const short8*)&x16[go0 * HD + k * 32 + quad * 8];
    }
    __syncthreads();   // sM visible

    // ---- phase B: transposed conv, nt-pipelined
    float ps0[4] = {0, 0, 0, 0}, ps1[4] = {0, 0, 0, 0};

#pragma unroll
    for (int nt = 0; nt < NTPB; ++nt) {
        int lo = nt * 16 + l15;
        long go = gbase + nbase + lo;
        short8 xn[4];
        if (!XF32 && nt + 1 < NTPB) {
            const unsigned short* x16 = (const unsigned short*)xin_v;
            long gn = go + 16;
#pragma unroll
            for (int k = 0; k < 4; ++k)
                xn[k] = *(const short8*)&x16[gn * HD + k * 32 + quad * 8];
        }
        floatx4 a0 = {b40.x, b40.y, b40.z, b40.w};
        floatx4 a1 = {b41.x, b41.y, b41.z, b41.w};
#pragma unroll
        for (int k = 0; k < 4; ++k) {
            short8 B0 = *(const short8*)&sM[lo * MSTR + k * 32 + quad * 8];
            a0 = __builtin_amdgcn_mfma_f32_16x16x32_bf16(Wr8[0][k], B0, a0, 0, 0, 0);
            a1 = __builtin_amdgcn_mfma_f32_16x16x32_bf16(Wr8[1][k], B0, a1, 0, 0, 0);
        }
        if (XF32) {
            const float4* xf = (const float4*)xin_v;
#pragma unroll
            for (int k = 0; k < 4; ++k) {
                float4 v0 = xf[go * 32 + k * 8 + quad * 2];
                float4 v1 = xf[go * 32 + k * 8 + quad * 2 + 1];
                short8 B1;
                B1[0] = (short)f2b(v0.x); B1[1] = (short)f2b(v0.y);
                B1[2] = (short)f2b(v0.z); B1[3] = (short)f2b(v0.w);
                B1[4] = (short)f2b(v1.x); B1[5] = (short)f2b(v1.y);
                B1[6] = (short)f2b(v1.z); B1[7] = (short)f2b(v1.w);
                a0 = __builtin_amdgcn_mfma_f32_16x16x32_bf16(Ws8[0][k], B1, a0, 0, 0, 0);
                a1 = __builtin_amdgcn_mfma_f32_16x16x32_bf16(Ws8[1][k], B1, a1, 0, 0, 0);
            }
        } else {
#pragma unroll
            for (int k = 0; k < 4; ++k) {
                a0 = __builtin_amdgcn_mfma_f32_16x16x32_bf16(Ws8[0][k], xc[k], a0, 0, 0, 0);
                a1 = __builtin_amdgcn_mfma_f32_16x16x32_bf16(Ws8[1][k], xc[k], a1, 0, 0, 0);
            }
        }
        bool liv = av[nt] != 0.0f;
        float v0r[4], v1r[4];
#pragma unroll
        for (int rr = 0; rr < 4; ++rr) {
            v0r[rr] = fmaxf(a0[rr], 0.0f);
            v1r[rr] = fmaxf(a1[rr], 0.0f);
            if (liv) { ps0[rr] += v0r[rr]; ps1[rr] += v1r[rr]; }
            if (!liv) { v0r[rr] = 0.0f; v1r[rr] = 0.0f; }
        }
        // node-major store
        unsigned short* orow = &xout[go * HD];
        uint2 w0, w1;
        w0.x = pk2(v0r[0], v0r[1]); w0.y = pk2(v0r[2], v0r[3]);
        w1.x = pk2(v1r[0], v1r[1]); w1.y = pk2(v1r[2], v1r[3]);
        *(uint2*)&orow[(2 * mp) * 16 + quad * 4] = w0;
        *(uint2*)&orow[(2 * mp + 1) * 16 + quad * 4] = w1;
        // feature-major store (acc layout is already OUT^T)
#pragma unroll
        for (int rr = 0; rr < 4; ++rr) {
            xtout[(long)(32 * mp + quad * 4 + rr) * NN + go] = f2b(v0r[rr]);
            xtout[(long)(32 * mp + 16 + quad * 4 + rr) * NN + go] = f2b(v1r[rr]);
        }
        // pool-score partial dots (wave's 32 features), reduce over quads, store per-mp slot
        if (dd) {
            float pr = v0r[0]*pwrA.x + v0r[1]*pwrA.y + v0r[2]*pwrA.z + v0r[3]*pwrA.w
                     + v1r[0]*pwrB.x + v1r[1]*pwrB.y + v1r[2]*pwrB.z + v1r[3]*pwrB.w;
            float pd = v0r[0]*pwsA.x + v0r[1]*pwsA.y + v0r[2]*pwsA.z + v0r[3]*pwsA.w
                     + v1r[0]*pwsB.x + v1r[1]*pwsB.y + v1r[2]*pwsB.z + v1r[3]*pwsB.w;
            pr += __shfl_xor(pr, 16); pr += __shfl_xor(pr, 32);
            pd += __shfl_xor(pd, 16); pd += __shfl_xor(pd, 32);
            if (quad == 0) {
                float2 st = {pr, pd};
                *(float2*)&dd[go * 8 + mp * 2] = st;
            }
        }
        if (!XF32 && nt + 1 < NTPB) {
#pragma unroll
            for (int k = 0; k < 4; ++k) xc[k] = xn[k];
        }
    }
    // fused readout: reduce over l15 (node lanes), atomic into hcat
#pragma unroll
    for (int rr = 0; rr < 4; ++rr) {
        float v = ps0[rr];
        v += __shfl_xor(v, 1); v += __shfl_xor(v, 2); v += __shfl_xor(v, 4); v += __shfl_xor(v, 8);
        float u = ps1[rr];
        u += __shfl_xor(u, 1); u += __shfl_xor(u, 2); u += __shfl_xor(u, 4); u += __shfl_xor(u, 8);
        if (l15 == 0) {
            atomicAdd(&hcat[g * (5 * HD) + layer * HD + (2 * mp) * 16 + quad * 4 + rr], v);
            atomicAdd(&hcat[g * (5 * HD) + layer * HD + (2 * mp + 1) * 16 + quad * 4 + rr], u);
        }
    }
}

// ---------------- pool v2: scores from precomputed dots; top-K; writes mult/alive/rliv only
__global__ __launch_bounds__(256) void k_pool2(
    const float* __restrict__ dd, float* __restrict__ multg,
    float* __restrict__ alive, float* __restrict__ rliv,
    const int* __restrict__ cnt, const int* __restrict__ col,
    const float* __restrict__ pb, int K)
{
    __shared__ float str[NPG0];
    __shared__ float stsb[NPG0];
    __shared__ float sal[NPG0];
    __shared__ float s[512];
    __shared__ float sc[NPG0];
    __shared__ unsigned char keep[NPG0];
    __shared__ int cnt_gt;
    int g = blockIdx.x, t = threadIdx.x;
    long nb = (long)g * NPG0;
    float pbv = pb[0];

    for (int n = t; n < NPG0; n += 256) {
        const float* dp = &dd[(nb + n) * 8];
        float4 da = *(const float4*)dp;
        float4 db = *(const float4*)(dp + 4);
        str[n] = da.x + da.z + db.x + db.z;          // x @ p_wr
        stsb[n] = da.y + da.w + db.y + db.w + pbv;   // x @ p_ws + b
        sal[n] = alive[nb + n];
    }
    if (t == 0) cnt_gt = 0;
    __syncthreads();

    for (int n = t; n < 512; n += 256) {
        float v = -INFINITY;
        if (n < NPG0 && sal[n] != 0.0f) {
            long o = nb + n;
            int m = cnt[o]; if (m > CAP) m = CAP;
            const int* cp = &col[o * (long)CAP];
            float ssum = 0.0f;
            for (int i = 0; i < m; i++) ssum += str[cp[i] - (int)nb];
            v = ssum * rliv[o] + stsb[n];
        }
        s[n] = v;
        if (n < NPG0) sc[n] = v;
    }
    __syncthreads();

    for (int ksz = 2; ksz <= 512; ksz <<= 1) {
        for (int jsz = ksz >> 1; jsz >= 1; jsz >>= 1) {
            for (int i = t; i < 512; i += 256) {
                int ixj = i ^ jsz;
                if (ixj > i) {
                    float a = s[i], c = s[ixj];
                    bool up = ((i & ksz) == 0);
                    if ((a > c) == up) { s[i] = c; s[ixj] = a; }
                }
            }
            __syncthreads();
        }
    }
    float thr = s[512 - K];
    for (int n = t; n < NPG0; n += 256)
        if (sc[n] > thr) atomicAdd(&cnt_gt, 1);
    __syncthreads();
    if (t == 0) {   // tie-break: lowest index (matches lax.top_k)
        int m = K - cnt_gt, tk = 0;
        for (int n = 0; n < NPG0; n++) {
            bool kp = sc[n] > thr;
            if (!kp && sc[n] == thr && tk < m) { kp = true; tk++; }
            keep[n] = kp ? 1 : 0;
        }
    }
    __syncthreads();
    for (int n = t; n < NPG0; n += 256) {
        multg[nb + n] = keep[n] ? tanhf(sc[n]) : 0.0f;
        alive[nb + n] = keep[n] ? 1.0f : 0.0f;
    }
    for (int n = t; n < NPG0; n += 256) {
        long o = nb + n;
        int m = cnt[o]; if (m > CAP) m = CAP;
        const int* cp = &col[o * (long)CAP];
        float ssum = 0.0f;
        for (int i = 0; i < m; i++) ssum += keep[cp[i] - (int)nb] ? 1.0f : 0.0f;
        rliv[o] = 1.0f / fmaxf(ssum, 1.0f);
    }
}

// ---------------- wide rescale: x (node-major) and xT (feature-major) *= mult[node]
__global__ __launch_bounds__(256) void k_scale(unsigned short* __restrict__ x,
    unsigned short* __restrict__ xt, const float* __restrict__ multg)
{
    int tid = blockIdx.x * 256 + threadIdx.x;
    const int step = SCGRID * 256;
    // node-major: NN*32 uint2 chunks
    for (int i = tid; i < NN * 32; i += step) {
        int n = i >> 5, c4 = i & 31;
        float m = multg[n];
        uint2* p = (uint2*)&x[(long)n * HD + c4 * 4];
        uint2 u = *p, w;
        w.x = pk2(b2f_lo(u.x) * m, b2f_hi(u.x) * m);
        w.y = pk2(b2f_lo(u.y) * m, b2f_hi(u.y) * m);
        *p = w;
    }
    // feature-major: 128 rows x NN/4 uint2 chunks (4 nodes each)
    for (int i = tid; i < HD * (NN / 4); i += step) {
        int f = i / (NN / 4), c = i - f * (NN / 4);
        int n4 = c * 4;
        unsigned short* p = &xt[(long)f * NN + n4];
        uint2 u = *(uint2*)p, w;
        w.x = pk2(b2f_lo(u.x) * multg[n4], b2f_hi(u.x) * multg[n4 + 1]);
        w.y = pk2(b2f_lo(u.y) * multg[n4 + 2], b2f_hi(u.y) * multg[n4 + 3]);
        *(uint2*)p = w;
    }
}

// ---------------- final MLP + log_softmax (hcat holds SUMS; divide here)
__global__ __launch_bounds__(128) void k_mlp(const float* __restrict__ h, const float* __restrict__ w1,
    const float* __restrict__ b1, const float* __restrict__ w2,
    const float* __restrict__ b2, float* __restrict__ out) {
    __shared__ float h1[HD];
    __shared__ float red[HD];
    __shared__ float lg[2];
    const float inv[5] = {1.0f/400.0f, 1.0f/400.0f, 1.0f/320.0f, 1.0f/320.0f, 1.0f/256.0f};
    int g = blockIdx.x, j = threadIdx.x;
    const float* hg = &h[g * (5 * HD)];
    float acc = b1[j];
    for (int k = 0; k < 5 * HD; k++) acc += hg[k] * inv[k >> 7] * w1[k * HD + j];
    h1[j] = fmaxf(acc, 0.0f);
    __syncthreads();
    for (int c = 0; c < 2; c++) {
        red[j] = h1[j] * w2[j * 2 + c];
        __syncthreads();
        for (int st = 64; st > 0; st >>= 1) {
            if (j < st) red[j] += red[j + st];
            __syncthreads();
        }
        if (j == 0) lg[c] = red[0] + b2[c];
        __syncthreads();
    }
    if (j == 0) {
        float l0 = lg[0], l1 = lg[1];
        float m = fmaxf(l0, l1);
        float lse = m + logf(expf(l0 - m) + expf(l1 - m));
        out[g * 2 + 0] = l0 - lse;
        out[g * 2 + 1] = l1 - lse;
    }
}

extern "C" void kernel_launch(void* const* d_in, const int* in_sizes, int n_in,
                              void* d_out, int out_size, void* d_ws, size_t ws_size,
                              hipStream_t stream) {
    const float* x_in   = (const float*)d_in[0];
    const int*   eidx   = (const int*)d_in[1];
    const int*   e_src  = eidx;
    const int*   e_dst  = eidx + NE;
    const float* c1_wr  = (const float*)d_in[3];
    const float* c1_ws  = (const float*)d_in[4];
    const float* c1_b   = (const float*)d_in[5];
    const float* cs_wr  = (const float*)d_in[6];
    const float* cs_ws  = (const float*)d_in[7];
    const float* cs_b   = (const float*)d_in[8];
    const float* p_wr   = (const float*)d_in[9];
    const float* p_ws   = (const float*)d_in[10];
    const float* p_b    = (const float*)d_in[11];
    const float* l1_w   = (const float*)d_in[12];
    const float* l1_b   = (const float*)d_in[13];
    const float* l2_w   = (const float*)d_in[14];
    const float* l2_b   = (const float*)d_in[15];
    float* out = (float*)d_out;

    char* ws = (char*)d_ws;
    size_t off = 0;
    int*   cnt   = (int*)(ws + off);             off += (size_t)NN * 4;
    int*   col   = (int*)(ws + off);             off += (size_t)NN * CAP * 4;
    float* alive = (float*)(ws + off);           off += (size_t)NN * 4;
    float* rliv  = (float*)(ws + off);           off += (size_t)NN * 4;
    unsigned short* xb0 = (unsigned short*)(ws + off); off += (size_t)NN * HD * 2;
    unsigned short* xb1 = (unsigned short*)(ws + off); off += (size_t)NN * HD * 2;
    float* hcat  = (float*)(ws + off);           off += (size_t)BGR * 5 * HD * 4;
    unsigned short* wbt = (unsigned short*)(ws + off); off += (size_t)10 * HD * HD * 2;
    unsigned char* Amat = (unsigned char*)(ws + off);  off += (size_t)NN * AST;
    unsigned short* xtA = (unsigned short*)(ws + off); off += ((size_t)NN * HD + 32) * 2;
    unsigned short* xtB = (unsigned short*)(ws + off); off += ((size_t)NN * HD + 32) * 2;
    float* dd    = (float*)(ws + off);           off += (size_t)NN * 8 * 4;
    float* multg = (float*)(ws + off);           off += (size_t)NN * 4;

    hipMemsetAsync(cnt, 0, (size_t)NN * 4, stream);
    hipMemsetAsync(hcat, 0, (size_t)BGR * 5 * HD * 4, stream);
    hipMemsetAsync(Amat, 0, (size_t)NN * AST, stream);
    // zero the 64B tails so the k=12 chunk of the last graph's last feature row reads zeros
    hipMemsetAsync(xtA + (size_t)NN * HD, 0, 64, stream);
    hipMemsetAsync(xtB + (size_t)NN * HD, 0, 64, stream);

    k_build<<<(NE + 255) / 256, 256, 0, stream>>>(e_src, e_dst, cnt, col);
    k_abuild<<<(NE + 255) / 256, 256, 0, stream>>>(e_src, e_dst, (unsigned int*)Amat);
    k_initrl<<<NN / 256, 256, 0, stream>>>(cnt, alive, rliv);
    k_wcvt<<<dim3(64, 10), 256, 0, stream>>>(c1_wr, c1_ws, cs_wr, cs_ws, wbt);
    k_xt0<<<dim3(200, 32), 512, 0, stream>>>(x_in, xtB);

    unsigned short* bt_wr[5] = { wbt + 0 * HD * HD, wbt + 2 * HD * HD, wbt + 3 * HD * HD, wbt + 4 * HD * HD, wbt + 5 * HD * HD };
    unsigned short* bt_ws[5] = { wbt + 1 * HD * HD, wbt + 6 * HD * HD, wbt + 7 * HD * HD, wbt + 8 * HD * HD, wbt + 9 * HD * HD };

    // conv1: x_in(fp32) -> xb0 ; xtB -> xtA
    k_layer5<true><<<dim3(BGR, NTPB), 256, 0, stream>>>(x_in, xb0, xtB, xtA, Amat, alive, rliv,
        bt_wr[0], bt_ws[0], c1_b, hcat, 0, nullptr, nullptr, nullptr);
    // convs[0]: xb0 -> xb1 ; xtA -> xtB ; pool0 dots
    k_layer5<false><<<dim3(BGR, NTPB), 256, 0, stream>>>(xb0, xb1, xtA, xtB, Amat, alive, rliv,
        bt_wr[1], bt_ws[1], cs_b + 0 * HD, hcat, 1, p_wr + 0 * HD, p_ws + 0 * HD, dd);
    // pool 0 (K=320)
    k_pool2<<<BGR, 256, 0, stream>>>(dd, multg, alive, rliv, cnt, col, p_b + 0, 320);
    k_scale<<<SCGRID, 256, 0, stream>>>(xb1, xtB, multg);
    // convs[1]: xb1 -> xb0 ; xtB -> xtA
    k_layer5<false><<<dim3(BGR, NTPB), 256, 0, stream>>>(xb1, xb0, xtB, xtA, Amat, alive, rliv,
        bt_wr[2], bt_ws[2], cs_b + 1 * HD, hcat, 2, nullptr, nullptr, nullptr);
    // convs[2]: xb0 -> xb1 ; xtA -> xtB ; pool1 dots
    k_layer5<false><<<dim3(BGR, NTPB), 256, 0, stream>>>(xb0, xb1, xtA, xtB, Amat, alive, rliv,
        bt_wr[3], bt_ws[3], cs_b + 2 * HD, hcat, 3, p_wr + 1 * HD, p_ws + 1 * HD, dd);
    // pool 1 (K=256)
    k_pool2<<<BGR, 256, 0, stream>>>(dd, multg, alive, rliv, cnt, col, p_b + 1, 256);
    k_scale<<<SCGRID, 256, 0, stream>>>(xb1, xtB, multg);
    // convs[3]: xb1 -> xb0 ; xtB -> xtA
    k_layer5<false><<<dim3(BGR, NTPB), 256, 0, stream>>>(xb1, xb0, xtB, xtA, Amat, alive, rliv,
        bt_wr[4], bt_ws[4], cs_b + 3 * HD, hcat, 4, nullptr, nullptr, nullptr);
    // MLP head
    k_mlp<<<BGR, HD, 0, stream>>>(hcat, l1_w, l1_b, l2_w, l2_b, out);
}

// Round 4
// 773.936 us; speedup vs baseline: 1.3876x; 1.3876x over previous
//
#include <hip/hip_runtime.h>
#include <math.h>

#define BGR 256        // graphs
#define NPG0 400       // nodes per graph
#define NN (BGR*NPG0)  // 102400 nodes
#define NE (NN*16)     // 1638400 edges
#define HD 128
#define CAP 64         // CSR capacity (pools only)
#define AST4 208       // u4 adjacency row stride BYTES (416 nibbles = 13*32)
#define KSA 13         // agg k-steps (13*32 = 416)
#define MSTR 136       // mean LDS row stride (shorts), 16B-aligned
#define NTPB 5         // node-tiles (of 16) per block; 5 blocks cover a graph

typedef __attribute__((ext_vector_type(8))) short short8;
typedef __attribute__((ext_vector_type(4))) float floatx4;

__device__ __forceinline__ unsigned short f2b(float f) {
    unsigned int u = __builtin_bit_cast(unsigned int, f);
    unsigned int r = (u + 0x7fffu + ((u >> 16) & 1u)) >> 16;
    return (unsigned short)r;
}
__device__ __forceinline__ unsigned int pk2(float a, float b) {
    return (unsigned int)f2b(a) | ((unsigned int)f2b(b) << 16);
}
__device__ __forceinline__ float b2f_lo(unsigned int u) { return __builtin_bit_cast(float, u << 16); }
__device__ __forceinline__ float b2f_hi(unsigned int u) { return __builtin_bit_cast(float, u & 0xffff0000u); }
__device__ __forceinline__ short bfint(unsigned int v) {
    // exact bf16 of small nonneg int (v < 256)
    return (short)(__builtin_bit_cast(unsigned int, (float)v) >> 16);
}
// u4 adjacency decode: 8 nibbles -> 8 bf16 counts
__device__ __forceinline__ short8 un4(unsigned int u) {
    short8 r;
#pragma unroll
    for (int j = 0; j < 8; ++j) r[j] = bfint((u >> (4 * j)) & 0xFu);
    return r;
}
// decode with per-src mult fold: bf16(count * m)
__device__ __forceinline__ short8 un4m(unsigned int u, float4 mA, float4 mB) {
    short8 r;
    r[0] = (short)f2b((float)(u & 0xFu) * mA.x);
    r[1] = (short)f2b((float)((u >> 4) & 0xFu) * mA.y);
    r[2] = (short)f2b((float)((u >> 8) & 0xFu) * mA.z);
    r[3] = (short)f2b((float)((u >> 12) & 0xFu) * mA.w);
    r[4] = (short)f2b((float)((u >> 16) & 0xFu) * mB.x);
    r[5] = (short)f2b((float)((u >> 20) & 0xFu) * mB.y);
    r[6] = (short)f2b((float)((u >> 24) & 0xFu) * mB.z);
    r[7] = (short)f2b((float)(u >> 28) * mB.w);
    return r;
}
// scale a bf16x8 fragment by scalar s (dst-node mult fold)
__device__ __forceinline__ short8 scale8(short8 v, float s) {
    short8 r;
#pragma unroll
    for (int j = 0; j < 8; ++j) {
        float f = __builtin_bit_cast(float, ((unsigned int)(unsigned short)v[j]) << 16);
        r[j] = (short)f2b(f * s);
    }
    return r;
}

// ---------------- merged graph build: CSR (pools) + u4 dense adjacency ----------------
__global__ void k_graph(const int* __restrict__ src, const int* __restrict__ dst,
                        int* __restrict__ cnt, int* __restrict__ col,
                        unsigned int* __restrict__ A) {
    int e = blockIdx.x * 256 + threadIdx.x;
    if (e >= NE) return;
    int d = dst[e], s = src[e];
    int i = atomicAdd(&cnt[d], 1);
    if (i < CAP) col[d * CAP + i] = s;
    int g = d / NPG0;
    long nib = (long)d * 416 + (s - g * NPG0);   // nibble index (416 nibbles/row)
    atomicAdd(&A[nib >> 3], 1u << ((nib & 7) * 4));
}

// alive=1, rliv = 1/max(deg,1) (exact degree incl. multi-edges)
__global__ void k_initrl(const int* __restrict__ cnt, float* __restrict__ alive,
                         float* __restrict__ rliv) {
    int i = blockIdx.x * 256 + threadIdx.x;
    if (i >= NN) return;
    alive[i] = 1.0f;
    rliv[i] = 1.0f / fmaxf((float)cnt[i], 1.0f);
}

// ---------------- W -> bf16, transposed: bt[m][j*128 + f] = bf16(W_m[f*128 + j]) = W^T row-major
__global__ void k_wcvt(const float* __restrict__ c1_wr, const float* __restrict__ c1_ws,
                       const float* __restrict__ cs_wr, const float* __restrict__ cs_ws,
                       unsigned short* __restrict__ bt) {
    int m = blockIdx.y;
    int idx = blockIdx.x * 256 + threadIdx.x;
    const float* W = (m == 0) ? c1_wr : (m == 1) ? c1_ws
                   : (m < 6) ? (cs_wr + (m - 2) * HD * HD) : (cs_ws + (m - 6) * HD * HD);
    int n = idx >> 7, k = idx & 127;
    bt[m * HD * HD + idx] = f2b(W[k * HD + n]);
}

// ---------------- one-time input cvt: x_in fp32 [NN][128] -> xT bf16 [128][NN] + x bf16 [NN][128]
__global__ __launch_bounds__(512) void k_xt0(const float* __restrict__ xin,
                                             unsigned short* __restrict__ xt,
                                             unsigned short* __restrict__ xb) {
    int t = threadIdx.x;
    int ngrp = blockIdx.x * 128 + (t >> 2);   // node group (4 nodes)
    int j = t & 3;
    int r0 = ngrp * 4;
    int f0 = blockIdx.y * 4;                  // feature group (4 feats)
    float4 v = ((const float4*)xin)[(long)(r0 + j) * 32 + (f0 >> 2)];
    // node-major bf16 copy (lane j owns node r0+j, feats f0..f0+3)
    uint2 nm; nm.x = pk2(v.x, v.y); nm.y = pk2(v.z, v.w);
    *(uint2*)&xb[(long)(r0 + j) * HD + f0] = nm;
    float a0 = v.x, a1 = v.y, a2 = v.z, a3 = v.w;
    float tw;
    bool bo1 = j & 1;
    tw = __shfl_xor(bo1 ? a0 : a1, 1); if (bo1) a0 = tw; else a1 = tw;
    tw = __shfl_xor(bo1 ? a2 : a3, 1); if (bo1) a2 = tw; else a3 = tw;
    bool bo2 = (j & 2) != 0;
    tw = __shfl_xor(bo2 ? a0 : a2, 2); if (bo2) a0 = tw; else a2 = tw;
    tw = __shfl_xor(bo2 ? a1 : a3, 2); if (bo2) a1 = tw; else a3 = tw;
    uint2 w; w.x = pk2(a0, a1); w.y = pk2(a2, a3);
    *(uint2*)&xt[(long)(f0 + j) * NN + r0] = w;
}

// ---------------- fused layer v6 = v4 core (depth-1 pipelined, global u4 adjacency)
//  + HASM: fold pool mult into agg decode (count*mult[src]) and conv-x frags (x*mult[dst])
//  + HASD: pool-score dot epilogue -> dd[n][mp][2]
template<bool HASM, bool HASD>
__global__ __launch_bounds__(256, 3) void k_layer6(
    const unsigned short* __restrict__ xin, unsigned short* __restrict__ xout,
    const unsigned short* __restrict__ xtin, unsigned short* __restrict__ xtout,
    const unsigned char* __restrict__ Amat,
    const float* __restrict__ alive, const float* __restrict__ rliv,
    const float* __restrict__ multg,
    const unsigned short* __restrict__ wr_bt, const unsigned short* __restrict__ ws_bt,
    const float* __restrict__ bias, float* __restrict__ hcat, int layer,
    const float* __restrict__ pwr, const float* __restrict__ pws, float* __restrict__ dd)
{
    __shared__ __align__(16) unsigned short sM[NTPB * 16 * MSTR];   // 80 x 136 shorts
    __shared__ __align__(16) float sMlt[416];
    int g = blockIdx.x;
    int ntg = blockIdx.y;
    int t = threadIdx.x;
    long gbase = (long)g * NPG0;
    int lane = t & 63, wid = t >> 6;          // 4 waves
    int quad = lane >> 4, l15 = lane & 15;
    int mp = wid;                              // feature pair-group: m-tiles 2mp, 2mp+1
    int nbase = ntg * (NTPB * 16);             // local dst-node base

    if (HASM) {
        for (int i = t; i < 416; i += 256) sMlt[i] = (i < NPG0) ? multg[gbase + i] : 0.0f;
    }

    // ---- phase A prologue: rliv, first xT frags, first adjacency dwords (all global, in flight)
    floatx4 acc[NTPB][2];
#pragma unroll
    for (int nt = 0; nt < NTPB; ++nt) {
        acc[nt][0] = (floatx4){0.f, 0.f, 0.f, 0.f};
        acc[nt][1] = (floatx4){0.f, 0.f, 0.f, 0.f};
    }
    const unsigned char* Ag = Amat + (gbase + nbase) * (long)AST4;
    const unsigned short* xa0 = xtin + (long)(mp * 32 + l15) * NN + gbase;
    const unsigned short* xa1 = xa0 + (long)16 * NN;

    float rl[NTPB];
#pragma unroll
    for (int nt = 0; nt < NTPB; ++nt) rl[nt] = rliv[gbase + nbase + nt * 16 + l15];

    short8 A0c = *(const short8*)&xa0[quad * 8];
    short8 A1c = *(const short8*)&xa1[quad * 8];
    unsigned int uc[NTPB];
#pragma unroll
    for (int nt = 0; nt < NTPB; ++nt)
        uc[nt] = *(const unsigned int*)&Ag[(long)(nt * 16 + l15) * AST4 + quad * 4];

    if (HASM) __syncthreads();   // sMlt visible
    float4 mAc, mBc;
    if (HASM) {
        mAc = *(const float4*)&sMlt[quad * 8];
        mBc = *(const float4*)&sMlt[quad * 8 + 4];
    }

    // ---- phase A: agg GEMM, k-outer, depth-1 pipelined
#pragma unroll
    for (int k = 0; k < KSA; ++k) {
        short8 A0n, A1n;
        unsigned int un[NTPB];
        float4 mAn, mBn;
        if (k + 1 < KSA) {
            int ko = (k + 1) * 32 + quad * 8;
            A0n = *(const short8*)&xa0[ko];
            A1n = *(const short8*)&xa1[ko];
#pragma unroll
            for (int nt = 0; nt < NTPB; ++nt)
                un[nt] = *(const unsigned int*)&Ag[(long)(nt * 16 + l15) * AST4 + (k + 1) * 16 + quad * 4];
            if (HASM) {
                mAn = *(const float4*)&sMlt[(k + 1) * 32 + quad * 8];
                mBn = *(const float4*)&sMlt[(k + 1) * 32 + quad * 8 + 4];
            }
        }
#pragma unroll
        for (int nt = 0; nt < NTPB; ++nt) {
            short8 Bf = HASM ? un4m(uc[nt], mAc, mBc) : un4(uc[nt]);
            acc[nt][0] = __builtin_amdgcn_mfma_f32_16x16x32_bf16(A0c, Bf, acc[nt][0], 0, 0, 0);
            acc[nt][1] = __builtin_amdgcn_mfma_f32_16x16x32_bf16(A1c, Bf, acc[nt][1], 0, 0, 0);
        }
        if (k + 1 < KSA) {
            A0c = A0n; A1c = A1n;
            if (HASM) { mAc = mAn; mBc = mBn; }
#pragma unroll
            for (int nt = 0; nt < NTPB; ++nt) uc[nt] = un[nt];
        }
    }
    // scale by rliv, write mean tile to LDS (node-major, local rows)
#pragma unroll
    for (int nt = 0; nt < NTPB; ++nt) {
        int lo = nt * 16 + l15;
        unsigned short* mrow = &sM[lo * MSTR + 32 * mp + quad * 4];
        uint2 w0, w1;
        w0.x = pk2(acc[nt][0][0] * rl[nt], acc[nt][0][1] * rl[nt]);
        w0.y = pk2(acc[nt][0][2] * rl[nt], acc[nt][0][3] * rl[nt]);
        w1.x = pk2(acc[nt][1][0] * rl[nt], acc[nt][1][1] * rl[nt]);
        w1.y = pk2(acc[nt][1][2] * rl[nt], acc[nt][1][3] * rl[nt]);
        *(uint2*)mrow = w0;
        *(uint2*)(mrow + 16) = w1;
    }

    // ---- pre-barrier issue: W frags, bias, alive, pool weights, nt=0 x rows
    short8 Wr8[2][4], Ws8[2][4];
#pragma unroll
    for (int mt = 0; mt < 2; ++mt) {
        int jj = (2 * mp + mt) * 16 + l15;
#pragma unroll
        for (int k = 0; k < 4; ++k) {
            Wr8[mt][k] = *(const short8*)&wr_bt[jj * HD + k * 32 + quad * 8];
            Ws8[mt][k] = *(const short8*)&ws_bt[jj * HD + k * 32 + quad * 8];
        }
    }
    float4 b40 = *(const float4*)&bias[(2 * mp) * 16 + quad * 4];
    float4 b41 = *(const float4*)&bias[(2 * mp + 1) * 16 + quad * 4];
    float av[NTPB];
#pragma unroll
    for (int nt = 0; nt < NTPB; ++nt) av[nt] = alive[gbase + nbase + nt * 16 + l15];

    float4 pwrA, pwrB, pwsA, pwsB;
    if (HASD) {
        pwrA = *(const float4*)&pwr[(2 * mp) * 16 + quad * 4];
        pwrB = *(const float4*)&pwr[(2 * mp + 1) * 16 + quad * 4];
        pwsA = *(const float4*)&pws[(2 * mp) * 16 + quad * 4];
        pwsB = *(const float4*)&pws[(2 * mp + 1) * 16 + quad * 4];
    }

    short8 xc[4];
    {
        long go0 = gbase + nbase + l15;
#pragma unroll
        for (int k = 0; k < 4; ++k)
            xc[k] = *(const short8*)&xin[go0 * HD + k * 32 + quad * 8];
    }
    __syncthreads();   // sM visible

    // ---- phase B: transposed conv, nt-pipelined
    float ps0[4] = {0, 0, 0, 0}, ps1[4] = {0, 0, 0, 0};

#pragma unroll
    for (int nt = 0; nt < NTPB; ++nt) {
        int lo = nt * 16 + l15;
        long go = gbase + nbase + lo;
        short8 xn[4];
        if (nt + 1 < NTPB) {
            long gn = go + 16;
#pragma unroll
            for (int k = 0; k < 4; ++k)
                xn[k] = *(const short8*)&xin[gn * HD + k * 32 + quad * 8];
        }
        floatx4 a0 = {b40.x, b40.y, b40.z, b40.w};
        floatx4 a1 = {b41.x, b41.y, b41.z, b41.w};
#pragma unroll
        for (int k = 0; k < 4; ++k) {
            short8 B0 = *(const short8*)&sM[lo * MSTR + k * 32 + quad * 8];
            a0 = __builtin_amdgcn_mfma_f32_16x16x32_bf16(Wr8[0][k], B0, a0, 0, 0, 0);
            a1 = __builtin_amdgcn_mfma_f32_16x16x32_bf16(Wr8[1][k], B0, a1, 0, 0, 0);
        }
        float sx;
        if (HASM) sx = sMlt[nbase + lo];
#pragma unroll
        for (int k = 0; k < 4; ++k) {
            short8 B1 = HASM ? scale8(xc[k], sx) : xc[k];
            a0 = __builtin_amdgcn_mfma_f32_16x16x32_bf16(Ws8[0][k], B1, a0, 0, 0, 0);
            a1 = __builtin_amdgcn_mfma_f32_16x16x32_bf16(Ws8[1][k], B1, a1, 0, 0, 0);
        }
        bool liv = av[nt] != 0.0f;
        float v0r[4], v1r[4];
#pragma unroll
        for (int rr = 0; rr < 4; ++rr) {
            v0r[rr] = fmaxf(a0[rr], 0.0f);
            v1r[rr] = fmaxf(a1[rr], 0.0f);
            if (liv) { ps0[rr] += v0r[rr]; ps1[rr] += v1r[rr]; }
            if (!liv) { v0r[rr] = 0.0f; v1r[rr] = 0.0f; }
        }
        // node-major store
        unsigned short* orow = &xout[go * HD];
        uint2 w0, w1;
        w0.x = pk2(v0r[0], v0r[1]); w0.y = pk2(v0r[2], v0r[3]);
        w1.x = pk2(v1r[0], v1r[1]); w1.y = pk2(v1r[2], v1r[3]);
        *(uint2*)&orow[(2 * mp) * 16 + quad * 4] = w0;
        *(uint2*)&orow[(2 * mp + 1) * 16 + quad * 4] = w1;
        // feature-major store (acc layout is already OUT^T)
#pragma unroll
        for (int rr = 0; rr < 4; ++rr) {
            xtout[(long)(32 * mp + quad * 4 + rr) * NN + go] = f2b(v0r[rr]);
            xtout[(long)(32 * mp + 16 + quad * 4 + rr) * NN + go] = f2b(v1r[rr]);
        }
        // pool-score partial dots (wave's 32 features), reduce over quads, store per-mp slot
        if (HASD) {
            float pr = v0r[0]*pwrA.x + v0r[1]*pwrA.y + v0r[2]*pwrA.z + v0r[3]*pwrA.w
                     + v1r[0]*pwrB.x + v1r[1]*pwrB.y + v1r[2]*pwrB.z + v1r[3]*pwrB.w;
            float pd = v0r[0]*pwsA.x + v0r[1]*pwsA.y + v0r[2]*pwsA.z + v0r[3]*pwsA.w
                     + v1r[0]*pwsB.x + v1r[1]*pwsB.y + v1r[2]*pwsB.z + v1r[3]*pwsB.w;
            pr += __shfl_xor(pr, 16); pr += __shfl_xor(pr, 32);
            pd += __shfl_xor(pd, 16); pd += __shfl_xor(pd, 32);
            if (quad == 0) {
                float2 st = {pr, pd};
                *(float2*)&dd[go * 8 + mp * 2] = st;
            }
        }
        if (nt + 1 < NTPB) {
#pragma unroll
            for (int k = 0; k < 4; ++k) xc[k] = xn[k];
        }
    }
    // fused readout: reduce over l15 (node lanes), atomic into hcat
#pragma unroll
    for (int rr = 0; rr < 4; ++rr) {
        float v = ps0[rr];
        v += __shfl_xor(v, 1); v += __shfl_xor(v, 2); v += __shfl_xor(v, 4); v += __shfl_xor(v, 8);
        float u = ps1[rr];
        u += __shfl_xor(u, 1); u += __shfl_xor(u, 2); u += __shfl_xor(u, 4); u += __shfl_xor(u, 8);
        if (l15 == 0) {
            atomicAdd(&hcat[g * (5 * HD) + layer * HD + (2 * mp) * 16 + quad * 4 + rr], v);
            atomicAdd(&hcat[g * (5 * HD) + layer * HD + (2 * mp + 1) * 16 + quad * 4 + rr], u);
        }
    }
}

// ---------------- pool v2: scores from precomputed dots; top-K; writes mult/alive/rliv only
__global__ __launch_bounds__(256) void k_pool2(
    const float* __restrict__ dd, float* __restrict__ multg,
    float* __restrict__ alive, float* __restrict__ rliv,
    const int* __restrict__ cnt, const int* __restrict__ col,
    const float* __restrict__ pb, int K)
{
    __shared__ float str[NPG0];
    __shared__ float stsb[NPG0];
    __shared__ float sal[NPG0];
    __shared__ float s[512];
    __shared__ float sc[NPG0];
    __shared__ unsigned char keep[NPG0];
    __shared__ int cnt_gt;
    int g = blockIdx.x, t = threadIdx.x;
    long nb = (long)g * NPG0;
    float pbv = pb[0];

    for (int n = t; n < NPG0; n += 256) {
        const float* dp = &dd[(nb + n) * 8];
        float4 da = *(const float4*)dp;
        float4 db = *(const float4*)(dp + 4);
        str[n] = da.x + da.z + db.x + db.z;          // x @ p_wr
        stsb[n] = da.y + da.w + db.y + db.w + pbv;   // x @ p_ws + b
        sal[n] = alive[nb + n];
    }
    if (t == 0) cnt_gt = 0;
    __syncthreads();

    for (int n = t; n < 512; n += 256) {
        float v = -INFINITY;
        if (n < NPG0 && sal[n] != 0.0f) {
            long o = nb + n;
            int m = cnt[o]; if (m > CAP) m = CAP;
            const int* cp = &col[o * (long)CAP];
            float ssum = 0.0f;
            for (int i = 0; i < m; i++) ssum += str[cp[i] - (int)nb];
            v = ssum * rliv[o] + stsb[n];
        }
        s[n] = v;
        if (n < NPG0) sc[n] = v;
    }
    __syncthreads();

    for (int ksz = 2; ksz <= 512; ksz <<= 1) {
        for (int jsz = ksz >> 1; jsz >= 1; jsz >>= 1) {
            for (int i = t; i < 512; i += 256) {
                int ixj = i ^ jsz;
                if (ixj > i) {
                    float a = s[i], c = s[ixj];
                    bool up = ((i & ksz) == 0);
                    if ((a > c) == up) { s[i] = c; s[ixj] = a; }
                }
            }
            __syncthreads();
        }
    }
    float thr = s[512 - K];
    for (int n = t; n < NPG0; n += 256)
        if (sc[n] > thr) atomicAdd(&cnt_gt, 1);
    __syncthreads();
    if (t == 0) {   // tie-break: lowest index (matches lax.top_k)
        int m = K - cnt_gt, tk = 0;
        for (int n = 0; n < NPG0; n++) {
            bool kp = sc[n] > thr;
            if (!kp && sc[n] == thr && tk < m) { kp = true; tk++; }
            keep[n] = kp ? 1 : 0;
        }
    }
    __syncthreads();
    for (int n = t; n < NPG0; n += 256) {
        multg[nb + n] = keep[n] ? tanhf(sc[n]) : 0.0f;
        alive[nb + n] = keep[n] ? 1.0f : 0.0f;
    }
    for (int n = t; n < NPG0; n += 256) {
        long o = nb + n;
        int m = cnt[o]; if (m > CAP) m = CAP;
        const int* cp = &col[o * (long)CAP];
        float ssum = 0.0f;
        for (int i = 0; i < m; i++) ssum += keep[cp[i] - (int)nb] ? 1.0f : 0.0f;
        rliv[o] = 1.0f / fmaxf(ssum, 1.0f);
    }
}

// ---------------- final MLP + log_softmax (hcat holds SUMS; divide here)
__global__ __launch_bounds__(128) void k_mlp(const float* __restrict__ h, const float* __restrict__ w1,
    const float* __restrict__ b1, const float* __restrict__ w2,
    const float* __restrict__ b2, float* __restrict__ out) {
    __shared__ float h1[HD];
    __shared__ float red[HD];
    __shared__ float lg[2];
    const float inv[5] = {1.0f/400.0f, 1.0f/400.0f, 1.0f/320.0f, 1.0f/320.0f, 1.0f/256.0f};
    int g = blockIdx.x, j = threadIdx.x;
    const float* hg = &h[g * (5 * HD)];
    float acc = b1[j];
    for (int k = 0; k < 5 * HD; k++) acc += hg[k] * inv[k >> 7] * w1[k * HD + j];
    h1[j] = fmaxf(acc, 0.0f);
    __syncthreads();
    for (int c = 0; c < 2; c++) {
        red[j] = h1[j] * w2[j * 2 + c];
        __syncthreads();
        for (int st = 64; st > 0; st >>= 1) {
            if (j < st) red[j] += red[j + st];
            __syncthreads();
        }
        if (j == 0) lg[c] = red[0] + b2[c];
        __syncthreads();
    }
    if (j == 0) {
        float l0 = lg[0], l1 = lg[1];
        float m = fmaxf(l0, l1);
        float lse = m + logf(expf(l0 - m) + expf(l1 - m));
        out[g * 2 + 0] = l0 - lse;
        out[g * 2 + 1] = l1 - lse;
    }
}

extern "C" void kernel_launch(void* const* d_in, const int* in_sizes, int n_in,
                              void* d_out, int out_size, void* d_ws, size_t ws_size,
                              hipStream_t stream) {
    const float* x_in   = (const float*)d_in[0];
    const int*   eidx   = (const int*)d_in[1];
    const int*   e_src  = eidx;
    const int*   e_dst  = eidx + NE;
    const float* c1_wr  = (const float*)d_in[3];
    const float* c1_ws  = (const float*)d_in[4];
    const float* c1_b   = (const float*)d_in[5];
    const float* cs_wr  = (const float*)d_in[6];
    const float* cs_ws  = (const float*)d_in[7];
    const float* cs_b   = (const float*)d_in[8];
    const float* p_wr   = (const float*)d_in[9];
    const float* p_ws   = (const float*)d_in[10];
    const float* p_b    = (const float*)d_in[11];
    const float* l1_w   = (const float*)d_in[12];
    const float* l1_b   = (const float*)d_in[13];
    const float* l2_w   = (const float*)d_in[14];
    const float* l2_b   = (const float*)d_in[15];
    float* out = (float*)d_out;

    char* ws = (char*)d_ws;
    size_t off = 0;
    int*   cnt   = (int*)(ws + off);             off += (size_t)NN * 4;
    int*   col   = (int*)(ws + off);             off += (size_t)NN * CAP * 4;
    float* alive = (float*)(ws + off);           off += (size_t)NN * 4;
    float* rliv  = (float*)(ws + off);           off += (size_t)NN * 4;
    unsigned short* xb0 = (unsigned short*)(ws + off); off += (size_t)NN * HD * 2;
    unsigned short* xb1 = (unsigned short*)(ws + off); off += (size_t)NN * HD * 2;
    float* hcat  = (float*)(ws + off);           off += (size_t)BGR * 5 * HD * 4;
    unsigned short* wbt = (unsigned short*)(ws + off); off += (size_t)10 * HD * HD * 2;
    unsigned char* Amat = (unsigned char*)(ws + off);  off += (size_t)NN * AST4;
    unsigned short* xtA = (unsigned short*)(ws + off); off += ((size_t)NN * HD + 32) * 2;
    unsigned short* xtB = (unsigned short*)(ws + off); off += ((size_t)NN * HD + 32) * 2;
    float* dd    = (float*)(ws + off);           off += (size_t)NN * 8 * 4;
    float* multg = (float*)(ws + off);           off += (size_t)NN * 4;

    hipMemsetAsync(cnt, 0, (size_t)NN * 4, stream);
    hipMemsetAsync(hcat, 0, (size_t)BGR * 5 * HD * 4, stream);
    hipMemsetAsync(Amat, 0, (size_t)NN * AST4, stream);
    // zero the tails so the k=12 chunk of the last graph's last feature row reads zeros
    hipMemsetAsync(xtA + (size_t)NN * HD, 0, 64, stream);
    hipMemsetAsync(xtB + (size_t)NN * HD, 0, 64, stream);

    k_graph<<<(NE + 255) / 256, 256, 0, stream>>>(e_src, e_dst, cnt, col, (unsigned int*)Amat);
    k_initrl<<<NN / 256, 256, 0, stream>>>(cnt, alive, rliv);
    k_wcvt<<<dim3(64, 10), 256, 0, stream>>>(c1_wr, c1_ws, cs_wr, cs_ws, wbt);
    k_xt0<<<dim3(200, 32), 512, 0, stream>>>(x_in, xtB, xb0);

    unsigned short* bt_wr[5] = { wbt + 0 * HD * HD, wbt + 2 * HD * HD, wbt + 3 * HD * HD, wbt + 4 * HD * HD, wbt + 5 * HD * HD };
    unsigned short* bt_ws[5] = { wbt + 1 * HD * HD, wbt + 6 * HD * HD, wbt + 7 * HD * HD, wbt + 8 * HD * HD, wbt + 9 * HD * HD };

    // L0 (conv1): xb0/xtB -> xb1/xtA
    k_layer6<false, false><<<dim3(BGR, NTPB), 256, 0, stream>>>(
        xb0, xb1, xtB, xtA, Amat, alive, rliv, nullptr,
        bt_wr[0], bt_ws[0], c1_b, hcat, 0, nullptr, nullptr, nullptr);
    // L1 (convs[0]) + pool0 dots: xb1/xtA -> xb0/xtB
    k_layer6<false, true><<<dim3(BGR, NTPB), 256, 0, stream>>>(
        xb1, xb0, xtA, xtB, Amat, alive, rliv, nullptr,
        bt_wr[1], bt_ws[1], cs_b + 0 * HD, hcat, 1, p_wr + 0 * HD, p_ws + 0 * HD, dd);
    // pool 0 (K=320)
    k_pool2<<<BGR, 256, 0, stream>>>(dd, multg, alive, rliv, cnt, col, p_b + 0, 320);
    // L2 (convs[1], folds mult): xb0/xtB -> xb1/xtA
    k_layer6<true, false><<<dim3(BGR, NTPB), 256, 0, stream>>>(
        xb0, xb1, xtB, xtA, Amat, alive, rliv, multg,
        bt_wr[2], bt_ws[2], cs_b + 1 * HD, hcat, 2, nullptr, nullptr, nullptr);
    // L3 (convs[2]) + pool1 dots: xb1/xtA -> xb0/xtB
    k_layer6<false, true><<<dim3(BGR, NTPB), 256, 0, stream>>>(
        xb1, xb0, xtA, xtB, Amat, alive, rliv, nullptr,
        bt_wr[3], bt_ws[3], cs_b + 2 * HD, hcat, 3, p_wr + 1 * HD, p_ws + 1 * HD, dd);
    // pool 1 (K=256)
    k_pool2<<<BGR, 256, 0, stream>>>(dd, multg, alive, rliv, cnt, col, p_b + 1, 256);
    // L4 (convs[3], folds mult): xb0/xtB -> xb1/xtA
    k_layer6<true, false><<<dim3(BGR, NTPB), 256, 0, stream>>>(
        xb0, xb1, xtB, xtA, Amat, alive, rliv, multg,
        bt_wr[4], bt_ws[4], cs_b + 3 * HD, hcat, 4, nullptr, nullptr, nullptr);
    // MLP head
    k_mlp<<<BGR, HD, 0, stream>>>(hcat, l1_w, l1_b, l2_w, l2_b, out);
}

// Round 5
// 604.390 us; speedup vs baseline: 1.7769x; 1.2805x over previous
//
#include <hip/hip_runtime.h>
#include <math.h>

#define BGR 256        // graphs
#define NPG0 400       // nodes per graph
#define NN (BGR*NPG0)  // 102400 nodes
#define NE (NN*16)     // 1638400 edges
#define HD 128
#define AST4 208       // u4 adjacency row stride BYTES (416 nibbles = 13*32)
#define A32PG (NPG0*52) // u32 words per graph adjacency slice = 20800
#define KSA 13         // agg k-steps (13*32 = 416)
#define MSTR 136       // LDS row stride (shorts), 16B-aligned
#define NTPB 5         // node-tiles (of 16) per block; 5 blocks cover a graph

typedef __attribute__((ext_vector_type(8))) short short8;
typedef __attribute__((ext_vector_type(4))) float floatx4;

__device__ __forceinline__ unsigned short f2b(float f) {
    unsigned int u = __builtin_bit_cast(unsigned int, f);
    unsigned int r = (u + 0x7fffu + ((u >> 16) & 1u)) >> 16;
    return (unsigned short)r;
}
__device__ __forceinline__ unsigned int pk2(float a, float b) {
    return (unsigned int)f2b(a) | ((unsigned int)f2b(b) << 16);
}
__device__ __forceinline__ float b2f_lo(unsigned int u) { return __builtin_bit_cast(float, u << 16); }
__device__ __forceinline__ float b2f_hi(unsigned int u) { return __builtin_bit_cast(float, u & 0xffff0000u); }
__device__ __forceinline__ short bfint(unsigned int v) {
    // exact bf16 of small nonneg int (v < 256)
    return (short)(__builtin_bit_cast(unsigned int, (float)v) >> 16);
}
// u4 adjacency decode: 8 nibbles -> 8 bf16 counts
__device__ __forceinline__ short8 un4(unsigned int u) {
    short8 r;
#pragma unroll
    for (int j = 0; j < 8; ++j) r[j] = bfint((u >> (4 * j)) & 0xFu);
    return r;
}
// decode with per-src mult fold: bf16(count * m)
__device__ __forceinline__ short8 un4m(unsigned int u, float4 mA, float4 mB) {
    short8 r;
    r[0] = (short)f2b((float)(u & 0xFu) * mA.x);
    r[1] = (short)f2b((float)((u >> 4) & 0xFu) * mA.y);
    r[2] = (short)f2b((float)((u >> 8) & 0xFu) * mA.z);
    r[3] = (short)f2b((float)((u >> 12) & 0xFu) * mA.w);
    r[4] = (short)f2b((float)((u >> 16) & 0xFu) * mB.x);
    r[5] = (short)f2b((float)((u >> 20) & 0xFu) * mB.y);
    r[6] = (short)f2b((float)((u >> 24) & 0xFu) * mB.z);
    r[7] = (short)f2b((float)(u >> 28) * mB.w);
    return r;
}
// 8-nibble dot with an LDS float vector (broadcast reads)
__device__ __forceinline__ float nibdot(unsigned int u, const float* v) {
    return (float)(u & 0xFu) * v[0] + (float)((u >> 4) & 0xFu) * v[1]
         + (float)((u >> 8) & 0xFu) * v[2] + (float)((u >> 12) & 0xFu) * v[3]
         + (float)((u >> 16) & 0xFu) * v[4] + (float)((u >> 20) & 0xFu) * v[5]
         + (float)((u >> 24) & 0xFu) * v[6] + (float)(u >> 28) * v[7];
}

// ---------------- per-graph build: LDS-atomic u4 adjacency + alive/rliv (no CSR) ----------------
__global__ __launch_bounds__(256) void k_graph2(const int* __restrict__ src,
                                                const int* __restrict__ dst,
                                                unsigned int* __restrict__ A,
                                                float* __restrict__ alive,
                                                float* __restrict__ rliv) {
    __shared__ unsigned int sA[A32PG];   // 83.2 KB
    int g = blockIdx.x, t = threadIdx.x;
    {
        uint4 z = {0u, 0u, 0u, 0u};
        uint4* s4 = (uint4*)sA;
        for (int i = t; i < A32PG / 4; i += 256) s4[i] = z;
    }
    __syncthreads();
    int ebase = g * (NPG0 * 16);
    int gb = g * NPG0;
    for (int i = t; i < NPG0 * 16; i += 256) {
        int s = src[ebase + i] - gb;
        int d = dst[ebase + i] - gb;
        int nib = d * 416 + s;
        atomicAdd(&sA[nib >> 3], 1u << ((nib & 7) * 4));
    }
    __syncthreads();
    {
        uint4* Ao = (uint4*)(A + (long)g * A32PG);
        const uint4* si = (const uint4*)sA;
        for (int i = t; i < A32PG / 4; i += 256) Ao[i] = si[i];
    }
    for (int n = t; n < NPG0; n += 256) {
        const unsigned int* row = &sA[n * 52];
        unsigned int deg = 0;
        for (int c = 0; c < 52; ++c) {
            unsigned int u = row[c];
            unsigned int p = (u & 0x0F0F0F0Fu) + ((u >> 4) & 0x0F0F0F0Fu);
            deg += (p * 0x01010101u) >> 24;
        }
        alive[gb + n] = 1.0f;
        rliv[gb + n] = 1.0f / fmaxf((float)deg, 1.0f);
    }
}

// ---------------- W -> bf16, transposed: bt[m][j*128 + f] = bf16(W_m[f*128 + j]) = W^T row-major
__global__ void k_wcvt(const float* __restrict__ c1_wr, const float* __restrict__ c1_ws,
                       const float* __restrict__ cs_wr, const float* __restrict__ cs_ws,
                       unsigned short* __restrict__ bt) {
    int m = blockIdx.y;
    int idx = blockIdx.x * 256 + threadIdx.x;
    const float* W = (m == 0) ? c1_wr : (m == 1) ? c1_ws
                   : (m < 6) ? (cs_wr + (m - 2) * HD * HD) : (cs_ws + (m - 6) * HD * HD);
    int n = idx >> 7, k = idx & 127;
    bt[m * HD * HD + idx] = f2b(W[k * HD + n]);
}

// ---------------- one-time input transpose: x_in fp32 [NN][128] -> xT bf16 [128][NN]
__global__ __launch_bounds__(512) void k_xt0(const float* __restrict__ xin,
                                             unsigned short* __restrict__ xt) {
    int t = threadIdx.x;
    int ngrp = blockIdx.x * 128 + (t >> 2);   // node group (4 nodes)
    int j = t & 3;
    int r0 = ngrp * 4;
    int f0 = blockIdx.y * 4;                  // feature group (4 feats)
    float4 v = ((const float4*)xin)[(long)(r0 + j) * 32 + (f0 >> 2)];
    float a0 = v.x, a1 = v.y, a2 = v.z, a3 = v.w;
    float tw;
    bool bo1 = j & 1;
    tw = __shfl_xor(bo1 ? a0 : a1, 1); if (bo1) a0 = tw; else a1 = tw;
    tw = __shfl_xor(bo1 ? a2 : a3, 1); if (bo1) a2 = tw; else a3 = tw;
    bool bo2 = (j & 2) != 0;
    tw = __shfl_xor(bo2 ? a0 : a2, 2); if (bo2) a0 = tw; else a2 = tw;
    tw = __shfl_xor(bo2 ? a1 : a3, 2); if (bo2) a1 = tw; else a3 = tw;
    uint2 w; w.x = pk2(a0, a1); w.y = pk2(a2, a3);
    *(uint2*)&xt[(long)(f0 + j) * NN + r0] = w;
}

// ---------------- fused layer v7: feature-major-only x.
//  phase A: agg GEMM (depth-1 pipelined, global u4 adjacency + xT A-frags);
//           prologue issues the conv x-tile staging loads (xT[:, block's 80 dst], 10 uint2/thread)
//  after k-loop: 4x4 shfl-transpose staging -> sX (node-major LDS tile) [HASM: * mult[dst]]
//  phase B: OUT^T = WrT.mean(sM) + WsT.x(sX) + b; relu/alive-gate; xT store (skip if LAST);
//           HASD: pool-score dots -> dd
template<bool HASM, bool HASD, bool LAST>
__global__ __launch_bounds__(256, 3) void k_layer7(
    const unsigned short* __restrict__ xtin, unsigned short* __restrict__ xtout,
    const unsigned char* __restrict__ Amat,
    const float* __restrict__ alive, const float* __restrict__ rliv,
    const float* __restrict__ multg,
    const unsigned short* __restrict__ wr_bt, const unsigned short* __restrict__ ws_bt,
    const float* __restrict__ bias, float* __restrict__ hcat, int layer,
    const float* __restrict__ pwr, const float* __restrict__ pws, float* __restrict__ dd)
{
    __shared__ __align__(16) unsigned short sM[NTPB * 16 * MSTR];   // mean tile, 21.8 KB
    __shared__ __align__(16) unsigned short sX[NTPB * 16 * MSTR];   // x tile (node-major), 21.8 KB
    __shared__ __align__(16) float sMlt[416];
    int g = blockIdx.x;
    int ntg = blockIdx.y;
    int t = threadIdx.x;
    long gbase = (long)g * NPG0;
    int lane = t & 63, wid = t >> 6;          // 4 waves
    int quad = lane >> 4, l15 = lane & 15;
    int mp = wid;                              // feature pair-group: m-tiles 2mp, 2mp+1
    int nbase = ntg * (NTPB * 16);             // local dst-node base
    int gi = t >> 2, j4 = t & 3;               // staging transpose group/lane

    if (HASM) {
        for (int i = t; i < 416; i += 256) sMlt[i] = (i < NPG0) ? multg[gbase + i] : 0.0f;
    }

    // ---- prologue: issue conv x-tile staging loads (xT[:, nbase..nbase+80), 640 4x4 tiles)
    uint2 stg[10];
#pragma unroll
    for (int it = 0; it < 10; ++it) {
        int tid2 = gi + it * 64;
        int fg = tid2 / 20, ng = tid2 - fg * 20;
        stg[it] = *(const uint2*)&xtin[(long)(fg * 4 + j4) * NN + gbase + nbase + ng * 4];
    }

    floatx4 acc[NTPB][2];
#pragma unroll
    for (int nt = 0; nt < NTPB; ++nt) {
        acc[nt][0] = (floatx4){0.f, 0.f, 0.f, 0.f};
        acc[nt][1] = (floatx4){0.f, 0.f, 0.f, 0.f};
    }
    const unsigned char* Ag = Amat + (gbase + nbase) * (long)AST4;
    const unsigned short* xa0 = xtin + (long)(mp * 32 + l15) * NN + gbase;
    const unsigned short* xa1 = xa0 + (long)16 * NN;

    float rl[NTPB];
#pragma unroll
    for (int nt = 0; nt < NTPB; ++nt) rl[nt] = rliv[gbase + nbase + nt * 16 + l15];

    short8 A0c = *(const short8*)&xa0[quad * 8];
    short8 A1c = *(const short8*)&xa1[quad * 8];
    unsigned int uc[NTPB];
#pragma unroll
    for (int nt = 0; nt < NTPB; ++nt)
        uc[nt] = *(const unsigned int*)&Ag[(long)(nt * 16 + l15) * AST4 + quad * 4];

    if (HASM) __syncthreads();   // sMlt visible
    float4 mAc, mBc;
    if (HASM) {
        mAc = *(const float4*)&sMlt[quad * 8];
        mBc = *(const float4*)&sMlt[quad * 8 + 4];
    }

    // ---- phase A: agg GEMM, k-outer, depth-1 pipelined
#pragma unroll
    for (int k = 0; k < KSA; ++k) {
        short8 A0n, A1n;
        unsigned int un[NTPB];
        float4 mAn, mBn;
        if (k + 1 < KSA) {
            int ko = (k + 1) * 32 + quad * 8;
            A0n = *(const short8*)&xa0[ko];
            A1n = *(const short8*)&xa1[ko];
#pragma unroll
            for (int nt = 0; nt < NTPB; ++nt)
                un[nt] = *(const unsigned int*)&Ag[(long)(nt * 16 + l15) * AST4 + (k + 1) * 16 + quad * 4];
            if (HASM) {
                mAn = *(const float4*)&sMlt[(k + 1) * 32 + quad * 8];
                mBn = *(const float4*)&sMlt[(k + 1) * 32 + quad * 8 + 4];
            }
        }
#pragma unroll
        for (int nt = 0; nt < NTPB; ++nt) {
            short8 Bf = HASM ? un4m(uc[nt], mAc, mBc) : un4(uc[nt]);
            acc[nt][0] = __builtin_amdgcn_mfma_f32_16x16x32_bf16(A0c, Bf, acc[nt][0], 0, 0, 0);
            acc[nt][1] = __builtin_amdgcn_mfma_f32_16x16x32_bf16(A1c, Bf, acc[nt][1], 0, 0, 0);
        }
        if (k + 1 < KSA) {
            A0c = A0n; A1c = A1n;
            if (HASM) { mAc = mAn; mBc = mBn; }
#pragma unroll
            for (int nt = 0; nt < NTPB; ++nt) uc[nt] = un[nt];
        }
    }

    // ---- staging transpose -> sX (node-major). lane j4 of each 4-lane group ends
    // holding node ng*4+j4's feats fg*4..fg*4+3. HASM folds mult[dst] here (bit-identical
    // to bf16(bf16(x)*m): a is the exact float of bf16 x).
#pragma unroll
    for (int it = 0; it < 10; ++it) {
        int tid2 = gi + it * 64;
        int fg = tid2 / 20, ng = tid2 - fg * 20;
        uint2 u = stg[it];
        float a0 = b2f_lo(u.x), a1 = b2f_hi(u.x), a2 = b2f_lo(u.y), a3 = b2f_hi(u.y);
        float tw;
        bool bo1 = j4 & 1;
        tw = __shfl_xor(bo1 ? a0 : a1, 1); if (bo1) a0 = tw; else a1 = tw;
        tw = __shfl_xor(bo1 ? a2 : a3, 1); if (bo1) a2 = tw; else a3 = tw;
        bool bo2 = (j4 & 2) != 0;
        tw = __shfl_xor(bo2 ? a0 : a2, 2); if (bo2) a0 = tw; else a2 = tw;
        tw = __shfl_xor(bo2 ? a1 : a3, 2); if (bo2) a1 = tw; else a3 = tw;
        if (HASM) {
            float m = sMlt[nbase + ng * 4 + j4];
            a0 *= m; a1 *= m; a2 *= m; a3 *= m;
        }
        uint2 w; w.x = pk2(a0, a1); w.y = pk2(a2, a3);
        *(uint2*)&sX[(ng * 4 + j4) * MSTR + fg * 4] = w;
    }

    // ---- scale by rliv, write mean tile to LDS (node-major, local rows)
#pragma unroll
    for (int nt = 0; nt < NTPB; ++nt) {
        int lo = nt * 16 + l15;
        unsigned short* mrow = &sM[lo * MSTR + 32 * mp + quad * 4];
        uint2 w0, w1;
        w0.x = pk2(acc[nt][0][0] * rl[nt], acc[nt][0][1] * rl[nt]);
        w0.y = pk2(acc[nt][0][2] * rl[nt], acc[nt][0][3] * rl[nt]);
        w1.x = pk2(acc[nt][1][0] * rl[nt], acc[nt][1][1] * rl[nt]);
        w1.y = pk2(acc[nt][1][2] * rl[nt], acc[nt][1][3] * rl[nt]);
        *(uint2*)mrow = w0;
        *(uint2*)(mrow + 16) = w1;
    }

    // ---- pre-barrier issue: W frags, bias, alive, pool weights
    short8 Wr8[2][4], Ws8[2][4];
#pragma unroll
    for (int mt = 0; mt < 2; ++mt) {
        int jj = (2 * mp + mt) * 16 + l15;
#pragma unroll
        for (int k = 0; k < 4; ++k) {
            Wr8[mt][k] = *(const short8*)&wr_bt[jj * HD + k * 32 + quad * 8];
            Ws8[mt][k] = *(const short8*)&ws_bt[jj * HD + k * 32 + quad * 8];
        }
    }
    float4 b40 = *(const float4*)&bias[(2 * mp) * 16 + quad * 4];
    float4 b41 = *(const float4*)&bias[(2 * mp + 1) * 16 + quad * 4];
    float av[NTPB];
#pragma unroll
    for (int nt = 0; nt < NTPB; ++nt) av[nt] = alive[gbase + nbase + nt * 16 + l15];

    float4 pwrA, pwrB, pwsA, pwsB;
    if (HASD) {
        pwrA = *(const float4*)&pwr[(2 * mp) * 16 + quad * 4];
        pwrB = *(const float4*)&pwr[(2 * mp + 1) * 16 + quad * 4];
        pwsA = *(const float4*)&pws[(2 * mp) * 16 + quad * 4];
        pwsB = *(const float4*)&pws[(2 * mp + 1) * 16 + quad * 4];
    }
    __syncthreads();   // sM + sX visible

    // ---- phase B: transposed conv, pure LDS operands
    float ps0[4] = {0, 0, 0, 0}, ps1[4] = {0, 0, 0, 0};

#pragma unroll
    for (int nt = 0; nt < NTPB; ++nt) {
        int lo = nt * 16 + l15;
        long go = gbase + nbase + lo;
        floatx4 a0 = {b40.x, b40.y, b40.z, b40.w};
        floatx4 a1 = {b41.x, b41.y, b41.z, b41.w};
#pragma unroll
        for (int k = 0; k < 4; ++k) {
            short8 B0 = *(const short8*)&sM[lo * MSTR + k * 32 + quad * 8];
            a0 = __builtin_amdgcn_mfma_f32_16x16x32_bf16(Wr8[0][k], B0, a0, 0, 0, 0);
            a1 = __builtin_amdgcn_mfma_f32_16x16x32_bf16(Wr8[1][k], B0, a1, 0, 0, 0);
        }
#pragma unroll
        for (int k = 0; k < 4; ++k) {
            short8 B1 = *(const short8*)&sX[lo * MSTR + k * 32 + quad * 8];
            a0 = __builtin_amdgcn_mfma_f32_16x16x32_bf16(Ws8[0][k], B1, a0, 0, 0, 0);
            a1 = __builtin_amdgcn_mfma_f32_16x16x32_bf16(Ws8[1][k], B1, a1, 0, 0, 0);
        }
        bool liv = av[nt] != 0.0f;
        float v0r[4], v1r[4];
#pragma unroll
        for (int rr = 0; rr < 4; ++rr) {
            v0r[rr] = fmaxf(a0[rr], 0.0f);
            v1r[rr] = fmaxf(a1[rr], 0.0f);
            if (liv) { ps0[rr] += v0r[rr]; ps1[rr] += v1r[rr]; }
            if (!liv) { v0r[rr] = 0.0f; v1r[rr] = 0.0f; }
        }
        if (!LAST) {
            // feature-major store (acc layout is already OUT^T)
#pragma unroll
            for (int rr = 0; rr < 4; ++rr) {
                xtout[(long)(32 * mp + quad * 4 + rr) * NN + go] = f2b(v0r[rr]);
                xtout[(long)(32 * mp + 16 + quad * 4 + rr) * NN + go] = f2b(v1r[rr]);
            }
        }
        // pool-score partial dots (wave's 32 features), reduce over quads, store per-mp slot
        if (HASD) {
            float pr = v0r[0]*pwrA.x + v0r[1]*pwrA.y + v0r[2]*pwrA.z + v0r[3]*pwrA.w
                     + v1r[0]*pwrB.x + v1r[1]*pwrB.y + v1r[2]*pwrB.z + v1r[3]*pwrB.w;
            float pd = v0r[0]*pwsA.x + v0r[1]*pwsA.y + v0r[2]*pwsA.z + v0r[3]*pwsA.w
                     + v1r[0]*pwsB.x + v1r[1]*pwsB.y + v1r[2]*pwsB.z + v1r[3]*pwsB.w;
            pr += __shfl_xor(pr, 16); pr += __shfl_xor(pr, 32);
            pd += __shfl_xor(pd, 16); pd += __shfl_xor(pd, 32);
            if (quad == 0) {
                float2 st = {pr, pd};
                *(float2*)&dd[go * 8 + mp * 2] = st;
            }
        }
    }
    // fused readout: reduce over l15 (node lanes), atomic into hcat
#pragma unroll
    for (int rr = 0; rr < 4; ++rr) {
        float v = ps0[rr];
        v += __shfl_xor(v, 1); v += __shfl_xor(v, 2); v += __shfl_xor(v, 4); v += __shfl_xor(v, 8);
        float u = ps1[rr];
        u += __shfl_xor(u, 1); u += __shfl_xor(u, 2); u += __shfl_xor(u, 4); u += __shfl_xor(u, 8);
        if (l15 == 0) {
            atomicAdd(&hcat[g * (5 * HD) + layer * HD + (2 * mp) * 16 + quad * 4 + rr], v);
            atomicAdd(&hcat[g * (5 * HD) + layer * HD + (2 * mp + 1) * 16 + quad * 4 + rr], u);
        }
    }
}

// ---------------- pool v3: dense-adjacency neighbor sums (no CSR); top-K; mult/alive/rliv
__global__ __launch_bounds__(256) void k_pool2(
    const float* __restrict__ dd, const unsigned int* __restrict__ A,
    float* __restrict__ multg, float* __restrict__ alive, float* __restrict__ rliv,
    const float* __restrict__ pb, int K)
{
    __shared__ float str[NPG0];
    __shared__ float stsb[NPG0];
    __shared__ float sal[NPG0];
    __shared__ float s[512];
    __shared__ float sc[NPG0];
    __shared__ float kf[NPG0];
    __shared__ unsigned char keep[NPG0];
    __shared__ int cnt_gt;
    int g = blockIdx.x, t = threadIdx.x;
    long nb = (long)g * NPG0;
    float pbv = pb[0];

    for (int n = t; n < NPG0; n += 256) {
        const float* dp = &dd[(nb + n) * 8];
        float4 da = *(const float4*)dp;
        float4 db = *(const float4*)(dp + 4);
        str[n] = da.x + da.z + db.x + db.z;          // x @ p_wr
        stsb[n] = da.y + da.w + db.y + db.w + pbv;   // x @ p_ws + b
        sal[n] = alive[nb + n];
    }
    if (t == 0) cnt_gt = 0;
    __syncthreads();

    for (int n = t; n < 512; n += 256) {
        float v = -INFINITY;
        if (n < NPG0 && sal[n] != 0.0f) {
            const uint4* Ar = (const uint4*)(A + ((long)g * NPG0 + n) * 52);
            float ssum = 0.0f;
#pragma unroll
            for (int c = 0; c < 13; ++c) {
                uint4 q = Ar[c];
                ssum += nibdot(q.x, &str[c * 32]);
                ssum += nibdot(q.y, &str[c * 32 + 8]);
                ssum += nibdot(q.z, &str[c * 32 + 16]);
                ssum += nibdot(q.w, &str[c * 32 + 24]);
            }
            v = ssum * rliv[nb + n] + stsb[n];
        }
        s[n] = v;
        if (n < NPG0) sc[n] = v;
    }
    __syncthreads();

    for (int ksz = 2; ksz <= 512; ksz <<= 1) {
        for (int jsz = ksz >> 1; jsz >= 1; jsz >>= 1) {
            for (int i = t; i < 512; i += 256) {
                int ixj = i ^ jsz;
                if (ixj > i) {
                    float a = s[i], c = s[ixj];
                    bool up = ((i & ksz) == 0);
                    if ((a > c) == up) { s[i] = c; s[ixj] = a; }
                }
            }
            __syncthreads();
        }
    }
    float thr = s[512 - K];
    for (int n = t; n < NPG0; n += 256)
        if (sc[n] > thr) atomicAdd(&cnt_gt, 1);
    __syncthreads();
    if (t == 0) {   // tie-break: lowest index (matches lax.top_k)
        int m = K - cnt_gt, tk = 0;
        for (int n = 0; n < NPG0; n++) {
            bool kp = sc[n] > thr;
            if (!kp && sc[n] == thr && tk < m) { kp = true; tk++; }
            keep[n] = kp ? 1 : 0;
        }
    }
    __syncthreads();
    for (int n = t; n < NPG0; n += 256) {
        multg[nb + n] = keep[n] ? tanhf(sc[n]) : 0.0f;
        alive[nb + n] = keep[n] ? 1.0f : 0.0f;
        kf[n] = keep[n] ? 1.0f : 0.0f;
    }
    __syncthreads();
    for (int n = t; n < NPG0; n += 256) {
        const uint4* Ar = (const uint4*)(A + ((long)g * NPG0 + n) * 52);
        float ssum = 0.0f;
#pragma unroll
        for (int c = 0; c < 13; ++c) {
            uint4 q = Ar[c];
            ssum += nibdot(q.x, &kf[c * 32]);
            ssum += nibdot(q.y, &kf[c * 32 + 8]);
            ssum += nibdot(q.z, &kf[c * 32 + 16]);
            ssum += nibdot(q.w, &kf[c * 32 + 24]);
        }
        rliv[nb + n] = 1.0f / fmaxf(ssum, 1.0f);
    }
}

// ---------------- final MLP + log_softmax (hcat holds SUMS; divide here)
__global__ __launch_bounds__(128) void k_mlp(const float* __restrict__ h, const float* __restrict__ w1,
    const float* __restrict__ b1, const float* __restrict__ w2,
    const float* __restrict__ b2, float* __restrict__ out) {
    __shared__ float h1[HD];
    __shared__ float red[HD];
    __shared__ float lg[2];
    const float inv[5] = {1.0f/400.0f, 1.0f/400.0f, 1.0f/320.0f, 1.0f/320.0f, 1.0f/256.0f};
    int g = blockIdx.x, j = threadIdx.x;
    const float* hg = &h[g * (5 * HD)];
    float acc = b1[j];
    for (int k = 0; k < 5 * HD; k++) acc += hg[k] * inv[k >> 7] * w1[k * HD + j];
    h1[j] = fmaxf(acc, 0.0f);
    __syncthreads();
    for (int c = 0; c < 2; c++) {
        red[j] = h1[j] * w2[j * 2 + c];
        __syncthreads();
        for (int st = 64; st > 0; st >>= 1) {
            if (j < st) red[j] += red[j + st];
            __syncthreads();
        }
        if (j == 0) lg[c] = red[0] + b2[c];
        __syncthreads();
    }
    if (j == 0) {
        float l0 = lg[0], l1 = lg[1];
        float m = fmaxf(l0, l1);
        float lse = m + logf(expf(l0 - m) + expf(l1 - m));
        out[g * 2 + 0] = l0 - lse;
        out[g * 2 + 1] = l1 - lse;
    }
}

extern "C" void kernel_launch(void* const* d_in, const int* in_sizes, int n_in,
                              void* d_out, int out_size, void* d_ws, size_t ws_size,
                              hipStream_t stream) {
    const float* x_in   = (const float*)d_in[0];
    const int*   eidx   = (const int*)d_in[1];
    const int*   e_src  = eidx;
    const int*   e_dst  = eidx + NE;
    const float* c1_wr  = (const float*)d_in[3];
    const float* c1_ws  = (const float*)d_in[4];
    const float* c1_b   = (const float*)d_in[5];
    const float* cs_wr  = (const float*)d_in[6];
    const float* cs_ws  = (const float*)d_in[7];
    const float* cs_b   = (const float*)d_in[8];
    const float* p_wr   = (const float*)d_in[9];
    const float* p_ws   = (const float*)d_in[10];
    const float* p_b    = (const float*)d_in[11];
    const float* l1_w   = (const float*)d_in[12];
    const float* l1_b   = (const float*)d_in[13];
    const float* l2_w   = (const float*)d_in[14];
    const float* l2_b   = (const float*)d_in[15];
    float* out = (float*)d_out;

    char* ws = (char*)d_ws;
    size_t off = 0;
    float* alive = (float*)(ws + off);           off += (size_t)NN * 4;
    float* rliv  = (float*)(ws + off);           off += (size_t)NN * 4;
    float* hcat  = (float*)(ws + off);           off += (size_t)BGR * 5 * HD * 4;
    unsigned short* wbt = (unsigned short*)(ws + off); off += (size_t)10 * HD * HD * 2;
    unsigned int* Amat = (unsigned int*)(ws + off);    off += (size_t)NN * 52 * 4;
    unsigned short* xtA = (unsigned short*)(ws + off); off += ((size_t)NN * HD + 32) * 2;
    unsigned short* xtB = (unsigned short*)(ws + off); off += ((size_t)NN * HD + 32) * 2;
    float* dd    = (float*)(ws + off);           off += (size_t)NN * 8 * 4;
    float* multg = (float*)(ws + off);           off += (size_t)NN * 4;

    hipMemsetAsync(hcat, 0, (size_t)BGR * 5 * HD * 4, stream);
    // zero the tails so the k=12 chunk of the last graph's last feature row reads zeros
    hipMemsetAsync(xtA + (size_t)NN * HD, 0, 64, stream);
    hipMemsetAsync(xtB + (size_t)NN * HD, 0, 64, stream);

    k_graph2<<<BGR, 256, 0, stream>>>(e_src, e_dst, Amat, alive, rliv);
    k_wcvt<<<dim3(64, 10), 256, 0, stream>>>(c1_wr, c1_ws, cs_wr, cs_ws, wbt);
    k_xt0<<<dim3(200, 32), 512, 0, stream>>>(x_in, xtB);

    unsigned short* bt_wr[5] = { wbt + 0 * HD * HD, wbt + 2 * HD * HD, wbt + 3 * HD * HD, wbt + 4 * HD * HD, wbt + 5 * HD * HD };
    unsigned short* bt_ws[5] = { wbt + 1 * HD * HD, wbt + 6 * HD * HD, wbt + 7 * HD * HD, wbt + 8 * HD * HD, wbt + 9 * HD * HD };
    const unsigned char* Am8 = (const unsigned char*)Amat;

    // L0 (conv1): xtB -> xtA
    k_layer7<false, false, false><<<dim3(BGR, NTPB), 256, 0, stream>>>(
        xtB, xtA, Am8, alive, rliv, nullptr,
        bt_wr[0], bt_ws[0], c1_b, hcat, 0, nullptr, nullptr, nullptr);
    // L1 (convs[0]) + pool0 dots: xtA -> xtB
    k_layer7<false, true, false><<<dim3(BGR, NTPB), 256, 0, stream>>>(
        xtA, xtB, Am8, alive, rliv, nullptr,
        bt_wr[1], bt_ws[1], cs_b + 0 * HD, hcat, 1, p_wr + 0 * HD, p_ws + 0 * HD, dd);
    // pool 0 (K=320)
    k_pool2<<<BGR, 256, 0, stream>>>(dd, Amat, multg, alive, rliv, p_b + 0, 320);
    // L2 (convs[1], folds mult): xtB -> xtA
    k_layer7<true, false, false><<<dim3(BGR, NTPB), 256, 0, stream>>>(
        xtB, xtA, Am8, alive, rliv, multg,
        bt_wr[2], bt_ws[2], cs_b + 1 * HD, hcat, 2, nullptr, nullptr, nullptr);
    // L3 (convs[2]) + pool1 dots: xtA -> xtB
    k_layer7<false, true, false><<<dim3(BGR, NTPB), 256, 0, stream>>>(
        xtA, xtB, Am8, alive, rliv, nullptr,
        bt_wr[3], bt_ws[3], cs_b + 2 * HD, hcat, 3, p_wr + 1 * HD, p_ws + 1 * HD, dd);
    // pool 1 (K=256)
    k_pool2<<<BGR, 256, 0, stream>>>(dd, Amat, multg, alive, rliv, p_b + 1, 256);
    // L4 (convs[3], folds mult, no x output): xtB -> (readout only)
    k_layer7<true, false, true><<<dim3(BGR, NTPB), 256, 0, stream>>>(
        xtB, nullptr, Am8, alive, rliv, multg,
        bt_wr[4], bt_ws[4], cs_b + 3 * HD, hcat, 4, nullptr, nullptr, nullptr);
    // MLP head
    k_mlp<<<BGR, HD, 0, stream>>>(hcat, l1_w, l1_b, l2_w, l2_b, out);
}